// Round 8
// baseline (120.350 us; speedup 1.0000x reference)
//
#include <hip/hip_runtime.h>

#define HW   256
#define HW2  (HW*HW)
#define KT   25
#define C    32

// float4 with 4-byte alignment: per-lane q loads start at clamp(w-2) which can be
// odd. gfx9+ global memory supports unaligned dwordx4; the relaxed align lets the
// backend emit global_load_dwordx4 without UB on the C++ side.
typedef float f4a4 __attribute__((ext_vector_type(4), aligned(4)));

// STRUCTURAL ABLATION (round 8): rounds 2-7 tuned the single-wave-block +
// global_load_lds ring architecture through 4 orthogonal null results
// (depth 1/2/4, occupancy 12/16 per CU, CPB 8/16, DMA width 4/16B) — per-channel
// iteration time pinned at ~5-6k cycles throughout. This kernel removes the whole
// structure: no LDS, no DMA, no vmcnt asm, multi-wave blocks, softmax ONCE per
// pixel (no channel-split redundancy), weights in pure VGPRs (25, not 50 -> no
// AGPR parking), per-channel loads through L1/L2 with compiler-scheduled waits.
__global__ __launch_bounds__(256, 4) void ddown_kernel(
    const float* __restrict__ x,
    const float* __restrict__ kern,
    float* __restrict__ out)
{
    const int w = threadIdx.x;            // one thread = one pixel column, all 32 ch
    const int h = blockIdx.x & (HW - 1);  // one block = one output row (4 waves)
    const int b = blockIdx.x >> 8;

    // Column-edge lane classes (only w = 0, 1, 255 differ from interior).
    const bool mB = (w == 0), mC = (w == 1), mD = (w == HW - 1);
    const int  wb = min(max(w - 2, 0), HW - 4);   // q covers cols wb..wb+3
    const int  ws = min(w + 2, HW - 1);           // s covers col  w+2

    // Row bases: h is block-uniform -> pure SALU, no per-lane cost.
    int hb[5];
#pragma unroll
    for (int di = 0; di < 5; ++di)
        hb[di] = min(max(h + di - 2, 0), HW - 1) * HW;

    // ---- softmax over the 25 taps, once per output pixel ----
    // Wave reads 256 B contiguous per tap; 25 independent loads into 25 VGPRs.
    const float* kb = kern + (size_t)b * KT * HW2 + h * HW + w;
    float wt[KT];
    float ssum = 0.f;
#pragma unroll
    for (int j = 0; j < KT; ++j) {
        float v = __expf(kb[(size_t)j * HW2]);
        ssum += v;
        wt[j] = v;
    }
    const float inv = 1.f / ssum;
#pragma unroll
    for (int j = 0; j < KT; ++j) wt[j] *= inv;

    // ---- fold the column clamp into the weights (once per pixel, not per channel) ----
    // Interior tap vector per row is {q.x,q.y,q.z,q.w,s} = x[wb..wb+3], x[ws].
    //  w=0  : q=x[0..3], s=x[2]; need (w0+w1+w2)x0 + w3*x1 + w4*x2 -> W={sum,w3,w4,0,0}
    //  w=1  : q=x[0..3], s=x[3]; need (w0+w1)x0 + w2*x1 + w3*x2 + w4*x3 -> W={w0+w1,w2,w3,w4,0}
    //  w=255: q=x[252..255], s=x[255]; need w0*x253 + w1*x254 + (w2+w3+w4)x255
    //         -> W={w0,w1,w2+w3+w4,0,0} on taps {x252,x253,x254,...}? No: taps are
    //            {q.x,q.y,q.z,q.w,s}={x252,x253,x254,x255,x255}: W={0? } ->
    //            shift: W0->tap1, W1->tap2, sum->tap3: {0,w0,w1,w2+w3+w4,0} is wrong
    //            order; verified mapping below: t0=x252 unused? need x253.. -> use
    //            W = {0,w0,w1,w2+w3+w4,0}? t1=x253*w0 t2=x254*w1 t3=x255*sum. YES.
#pragma unroll
    for (int di = 0; di < 5; ++di) {
        float w0 = wt[di*5+0], w1 = wt[di*5+1], w2 = wt[di*5+2],
              w3 = wt[di*5+3], w4 = wt[di*5+4];
        float n0 = mD ? 0.f            : (mB ? (w0 + w1 + w2) : (mC ? (w0 + w1) : w0));
        float n1 = mD ? w0             : (mB ? w3 : (mC ? w2 : w1));
        float n2 = mD ? w1             : (mB ? w4 : (mC ? w3 : w2));
        float n3 = mD ? (w2 + w3 + w4) : (mB ? 0.f : (mC ? w4 : w3));
        float n4 = (mB || mC || mD) ? 0.f : w4;
        wt[di*5+0] = n0; wt[di*5+1] = n1; wt[di*5+2] = n2;
        wt[di*5+3] = n3; wt[di*5+4] = n4;
    }

    const float* xb = x   + (size_t)b * C * HW2;
    float*       ob = out + (size_t)b * C * HW2 + h * HW + w;

    // ---- 32 channels, branchless; compiler pipelines loads across iterations ----
#pragma unroll
    for (int c = 0; c < C; ++c) {
        const float* xc = xb + (size_t)c * HW2;
        float acc = 0.f;
#pragma unroll
        for (int di = 0; di < 5; ++di) {
            const float* r = xc + hb[di];
            f4a4  q  = *(const f4a4*)(r + wb);
            float sv = r[ws];
            acc += wt[di*5+0] * q.x + wt[di*5+1] * q.y + wt[di*5+2] * q.z
                 + wt[di*5+3] * q.w + wt[di*5+4] * sv;
        }
        ob[(size_t)c * HW2] = acc;   // wave stores 256 B contiguous per channel
    }
}

extern "C" void kernel_launch(void* const* d_in, const int* in_sizes, int n_in,
                              void* d_out, int out_size, void* d_ws, size_t ws_size,
                              hipStream_t stream) {
    const float* x    = (const float*)d_in[0];
    const float* kern = (const float*)d_in[1];
    float* out        = (float*)d_out;

    dim3 grid(4 * HW);   // (b,h): 1024 blocks x 256 threads = 4 blocks/CU, one batch
    ddown_kernel<<<grid, 256, 0, stream>>>(x, kern, out);
}